// Round 1
// 628.962 us; speedup vs baseline: 1.1822x; 1.1822x over previous
//
#include <hip/hip_runtime.h>

typedef unsigned short u16;
using bf16x8 = __attribute__((ext_vector_type(8))) __bf16;
using f32x4  = __attribute__((ext_vector_type(4))) float;

// B=2, T=2048, D=4096, H=32, HD=128, HKV=1. M = B*T = 4096 token rows.

__device__ __forceinline__ u16 f2b(float f) {
    union { float f; unsigned int i; } x; x.f = f;
    unsigned int i = x.i + (((x.i >> 16) & 1u) + 0x7fffu);  // RNE
    return (u16)(i >> 16);
}
__device__ __forceinline__ u16 f2b_ru(float f) {
    union { float f; unsigned int i; } x; x.f = f;
    return (u16)((x.i + 0x8000u) >> 16);
}
__device__ __forceinline__ void gload_lds16(const u16* g, u16* l) {
    __builtin_amdgcn_global_load_lds((const __attribute__((address_space(1))) void*)g,
                                     (__attribute__((address_space(3))) void*)l, 16, 0, 0);
}

// ---- fp32 -> bf16 conversion (vectorized, 8 elems/thread) ----
__global__ __launch_bounds__(256) void cvt_f32_bf16(const float* __restrict__ in,
                                                    u16* __restrict__ out, int n) {
    int i = (blockIdx.x * 256 + threadIdx.x) * 8;
    if (i >= n) return;
    float4 a = *(const float4*)(in + i);
    float4 b = *(const float4*)(in + i + 4);
    union { u16 u[8]; uint4 v; } o;
    o.u[0] = f2b(a.x); o.u[1] = f2b(a.y); o.u[2] = f2b(a.z); o.u[3] = f2b(a.w);
    o.u[4] = f2b(b.x); o.u[5] = f2b(b.y); o.u[6] = f2b(b.z); o.u[7] = f2b(b.w);
    *(uint4*)(out + i) = o.v;
}

// =====================================================================
// 256x256-tile 8-phase GEMM core (C = A * W^T, both row-major, K-stride 4096)
// 8 waves (2M x 4N), BK=64, double-buffered 128 KiB LDS, st_16x32 swizzle.
// LDS is linear for global_load_lds; swizzle is applied by permuting the
// per-lane GLOBAL source (rule #21) and un-permuting on the ds_read side.
// Each gload instruction fills exactly one 16x32 (1 KiB) subtile.
// Schedule per K-tile u (quadrants (mh,nh) serpentine 00,01,11,10):
//   P1: read A[mh0](8xb128)+B[nh0](4) | stage (u+1).Amh1 -> other buf
//   P2: read B[nh1](4)                | stage (u+1).Bnh0 -> other buf
//   P3: read A[mh1](8)                | stage (u+2).Amh0 -> this buf (region died @P2)
//   P4: read B[nh0](4)                | stage (u+2).Bnh1 -> this buf (died @P3)
//        ... MFMA ... vmcnt(4) (never 0 in main loop) ...
// Every stage lands in a region whose last reader drained >=1 barrier earlier.
// =====================================================================

#define G_BAR()   __builtin_amdgcn_s_barrier()
#define G_LGKM0() asm volatile("s_waitcnt lgkmcnt(0)" ::: "memory")

struct GCtx {
    const u16* gA; const u16* gB;   // per-lane pre-swizzled staging sources
    int fro;                        // swizzled frag-read offset within subtile (u16)
    int dst;                        // lane dest within subtile (u16) = lane*8
    int wmi, wni;                   // wave tile coords (2 x 4)
    int rgA0, rgA1, rgB0, rgB1;     // per-wave rowgroup assignments for half-stages
    int w;
};

__device__ __forceinline__ void stg2(const GCtx& c, const u16* gb, int rg, int kt, u16* sb) {
    const u16* src = gb + (size_t)rg * 65536 + (size_t)kt * 64;   // rg*16 rows * 4096
    u16* d = sb + rg * 1024 + c.dst;                               // subtile (rg,cg) base
    gload_lds16(src,      d);
    gload_lds16(src + 32, d + 512);
}

template<int MODE>  // 0 = steady, 1 = first epilogue tile, 2 = last tile
__device__ __forceinline__ void tile_step(const GCtx& c, int u,
        u16* __restrict__ cA, u16* __restrict__ cB,
        u16* __restrict__ nA, u16* __restrict__ nB,
        f32x4 (&acc)[8][4]) {
    bf16x8 af[4][2], bf[2][2];
    // ---------------- P1: quadrant (mh0, nh0) ----------------
#pragma unroll
    for (int i = 0; i < 4; ++i) {
        const u16* p = cA + (((c.wmi * 8 + i) * 2) << 9) + c.fro;
        af[i][0] = *(const bf16x8*)(p);
        af[i][1] = *(const bf16x8*)(p + 512);
    }
#pragma unroll
    for (int n = 0; n < 2; ++n) {
        const u16* p = cB + (((c.wni * 4 + n) * 2) << 9) + c.fro;
        bf[n][0] = *(const bf16x8*)(p);
        bf[n][1] = *(const bf16x8*)(p + 512);
    }
    if (MODE < 2) stg2(c, c.gA, c.rgA1, u + 1, nA);
    G_BAR(); G_LGKM0();
    __builtin_amdgcn_s_setprio(1);
#pragma unroll
    for (int i = 0; i < 4; ++i)
#pragma unroll
        for (int n = 0; n < 2; ++n) {
            acc[i][n] = __builtin_amdgcn_mfma_f32_16x16x32_bf16(af[i][0], bf[n][0], acc[i][n], 0, 0, 0);
            acc[i][n] = __builtin_amdgcn_mfma_f32_16x16x32_bf16(af[i][1], bf[n][1], acc[i][n], 0, 0, 0);
        }
    __builtin_amdgcn_s_setprio(0);
    G_BAR();
    // ---------------- P2: quadrant (mh0, nh1) ----------------
#pragma unroll
    for (int n = 0; n < 2; ++n) {
        const u16* p = cB + (((c.wni * 4 + 2 + n) * 2) << 9) + c.fro;
        bf[n][0] = *(const bf16x8*)(p);
        bf[n][1] = *(const bf16x8*)(p + 512);
    }
    if (MODE < 2) stg2(c, c.gB, c.rgB0, u + 1, nB);
    G_BAR(); G_LGKM0();
    __builtin_amdgcn_s_setprio(1);
#pragma unroll
    for (int i = 0; i < 4; ++i)
#pragma unroll
        for (int n = 0; n < 2; ++n) {
            acc[i][2 + n] = __builtin_amdgcn_mfma_f32_16x16x32_bf16(af[i][0], bf[n][0], acc[i][2 + n], 0, 0, 0);
            acc[i][2 + n] = __builtin_amdgcn_mfma_f32_16x16x32_bf16(af[i][1], bf[n][1], acc[i][2 + n], 0, 0, 0);
        }
    __builtin_amdgcn_s_setprio(0);
    G_BAR();
    // ---------------- P3: quadrant (mh1, nh1) ----------------
#pragma unroll
    for (int i = 0; i < 4; ++i) {
        const u16* p = cA + (((c.wmi * 8 + 4 + i) * 2) << 9) + c.fro;
        af[i][0] = *(const bf16x8*)(p);
        af[i][1] = *(const bf16x8*)(p + 512);
    }
    if (MODE == 0) stg2(c, c.gA, c.rgA0, u + 2, cA);
    G_BAR(); G_LGKM0();
    __builtin_amdgcn_s_setprio(1);
#pragma unroll
    for (int i = 0; i < 4; ++i)
#pragma unroll
        for (int n = 0; n < 2; ++n) {
            acc[4 + i][2 + n] = __builtin_amdgcn_mfma_f32_16x16x32_bf16(af[i][0], bf[n][0], acc[4 + i][2 + n], 0, 0, 0);
            acc[4 + i][2 + n] = __builtin_amdgcn_mfma_f32_16x16x32_bf16(af[i][1], bf[n][1], acc[4 + i][2 + n], 0, 0, 0);
        }
    __builtin_amdgcn_s_setprio(0);
    G_BAR();
    // ---------------- P4: quadrant (mh1, nh0) ----------------
#pragma unroll
    for (int n = 0; n < 2; ++n) {
        const u16* p = cB + (((c.wni * 4 + n) * 2) << 9) + c.fro;
        bf[n][0] = *(const bf16x8*)(p);
        bf[n][1] = *(const bf16x8*)(p + 512);
    }
    if (MODE == 0) stg2(c, c.gB, c.rgB1, u + 2, cB);
    G_BAR(); G_LGKM0();
    __builtin_amdgcn_s_setprio(1);
#pragma unroll
    for (int i = 0; i < 4; ++i)
#pragma unroll
        for (int n = 0; n < 2; ++n) {
            acc[4 + i][n] = __builtin_amdgcn_mfma_f32_16x16x32_bf16(af[i][0], bf[n][0], acc[4 + i][n], 0, 0, 0);
            acc[4 + i][n] = __builtin_amdgcn_mfma_f32_16x16x32_bf16(af[i][1], bf[n][1], acc[4 + i][n], 0, 0, 0);
        }
    __builtin_amdgcn_s_setprio(0);
    if (MODE == 0) asm volatile("s_waitcnt vmcnt(4)" ::: "memory");
    if (MODE == 1) asm volatile("s_waitcnt vmcnt(0)" ::: "memory");
    G_BAR();
}

template<int NT>
__device__ __forceinline__ void gemm256(const u16* __restrict__ Ag,
                                        const u16* __restrict__ Bg,
                                        u16* __restrict__ lds,
                                        f32x4 (&acc)[8][4]) {
    const int t = threadIdx.x, l = t & 63, w = t >> 6;
    const int r = l & 15, qd = l >> 4, lr = l >> 2;
    const int co = ((l & 3) * 8) ^ (((l >> 5) & 1) << 4);  // inverse st_16x32 swizzle on source
    GCtx c;
    c.w = w; c.wmi = w >> 2; c.wni = w & 3;
    c.gA = Ag + (size_t)lr * 4096 + co;
    c.gB = Bg + (size_t)lr * 4096 + co;
    c.fro = r * 32 + ((qd * 8) ^ (((r >> 3) & 1) << 4));   // swizzled frag read
    c.dst = l * 8;
    c.rgA0 = (w & 3) | ((w & 4) << 1);        // {0,1,2,3,8,9,10,11}[w]
    c.rgA1 = c.rgA0 + 4;                       // {4..7,12..15}
    c.rgB0 = (w & 1) | ((w >> 1) << 2);        // {0,1,4,5,8,9,12,13}[w]
    c.rgB1 = c.rgB0 + 2;                       // {2,3,6,7,10,11,14,15}
    u16* sA0 = lds;          u16* sB0 = lds + 16384;
    u16* sA1 = lds + 32768;  u16* sB1 = lds + 49152;
#pragma unroll
    for (int i = 0; i < 8; ++i)
#pragma unroll
        for (int n = 0; n < 4; ++n) acc[i][n] = (f32x4){0.f, 0.f, 0.f, 0.f};
    // prologue: tile0 full (8 loads) + tile1 Amh0,Bnh1 (4 loads)
    stg2(c, c.gA, w, 0, sA0);     stg2(c, c.gA, w + 8, 0, sA0);
    stg2(c, c.gB, w, 0, sB0);     stg2(c, c.gB, w + 8, 0, sB0);
    stg2(c, c.gA, c.rgA0, 1, sA1);
    stg2(c, c.gB, c.rgB1, 1, sB1);
    asm volatile("s_waitcnt vmcnt(4)" ::: "memory");   // tile0 landed; tile1 in flight
    G_BAR();
#pragma unroll 1
    for (int u = 0; u + 2 < NT; u += 2) {
        tile_step<0>(c, u,     sA0, sB0, sA1, sB1, acc);
        tile_step<0>(c, u + 1, sA1, sB1, sA0, sB0, acc);
    }
    tile_step<1>(c, NT - 2, sA0, sB0, sA1, sB1, acc);
    tile_step<2>(c, NT - 1, sA1, sB1, sA0, sB0, acc);
}

// ---- Q projection: C = x * wq^T, pre-scaled. grid 256 (16x16, XCD-swizzled) ----
__global__ __launch_bounds__(512, 2) void q_gemm(
    const u16* __restrict__ x, const u16* __restrict__ wq,
    const float* __restrict__ wqb, u16* __restrict__ Qb) {
    __shared__ __align__(16) u16 lds[65536];   // 128 KiB
    int bid = blockIdx.x;
    int wgid = (bid & 7) * 32 + (bid >> 3);    // bijective (256 = 8*32)
    int brow = wgid >> 4, bcol = wgid & 15;
    f32x4 acc[8][4];
    gemm256<64>(x + (size_t)brow * 256 * 4096, wq + (size_t)bcol * 256 * 4096, lds, acc);
    const int t = threadIdx.x, l = t & 63, w = t >> 6;
    const int wmi = w >> 2, wni = w & 3, r = l & 15, qd = l >> 4;
    const float QSCALE = 0.08838834764831845f * 1.4426950408889634f;  // 1/sqrt(128)*log2(e)
#pragma unroll
    for (int n = 0; n < 4; ++n) {
        int col = bcol * 256 + wni * 64 + n * 16 + r;
        float bv = wqb[col];
#pragma unroll
        for (int mt = 0; mt < 8; ++mt)
#pragma unroll
            for (int j = 0; j < 4; ++j) {
                int m = brow * 256 + wmi * 128 + mt * 16 + qd * 4 + j;
                Qb[(size_t)m * 4096 + col] = f2b((acc[mt][n][j] + bv) * QSCALE);
            }
    }
}

// ---- K/V projection: K-split 8-phase GEMM into f32 partials. grid (16, 8) ----
// wkv = wk(128 rows) | wv(128 rows) contiguous. P[slice][m][256] f32.
__global__ __launch_bounds__(512, 2) void kv_gemm(
    const u16* __restrict__ x, const u16* __restrict__ wkv,
    float* __restrict__ P) {
    __shared__ __align__(16) u16 lds[65536];
    int brow = blockIdx.x;      // 0..15
    int slice = blockIdx.y;     // 0..7 (K chunk of 512)
    f32x4 acc[8][4];
    gemm256<8>(x + (size_t)brow * 256 * 4096 + slice * 512,
               wkv + slice * 512, lds, acc);
    const int t = threadIdx.x, l = t & 63, w = t >> 6;
    const int wmi = w >> 2, wni = w & 3, r = l & 15, qd = l >> 4;
    float* Pb = P + (size_t)slice * 4096 * 256;
#pragma unroll
    for (int n = 0; n < 4; ++n) {
        int nl = wni * 64 + n * 16 + r;
#pragma unroll
        for (int mt = 0; mt < 8; ++mt)
#pragma unroll
            for (int j = 0; j < 4; ++j) {
                int m = brow * 256 + wmi * 128 + mt * 16 + qd * 4 + j;
                Pb[(size_t)m * 256 + nl] = acc[mt][n][j];
            }
    }
}

// ---- reduce 8 K/V partials + bias -> Kb / Vt(bf16). grid 4096x256 ----
__global__ __launch_bounds__(256) void kv_reduce(const float* __restrict__ P,
        const float* __restrict__ wkb, const float* __restrict__ wvb,
        u16* __restrict__ Kb, u16* __restrict__ Vt) {
    int t = blockIdx.x * 256 + threadIdx.x;
    if (blockIdx.x < 2048) {                   // K half: nl fastest -> coalesced Kb
        int m = t >> 7, nl = t & 127;
        float s = 0.f;
#pragma unroll
        for (int sl = 0; sl < 8; ++sl) s += P[((size_t)sl * 4096 + m) * 256 + nl];
        Kb[(size_t)m * 128 + nl] = f2b(s + wkb[nl]);
    } else {                                    // V half: m fastest -> coalesced Vt rows
        int idx = t - 524288;
        int d = idx >> 12, m = idx & 4095;
        float s = 0.f;
#pragma unroll
        for (int sl = 0; sl < 8; ++sl) s += P[((size_t)sl * 4096 + m) * 256 + 128 + d];
        Vt[(size_t)d * 4096 + m] = f2b(s + wvb[d]);
    }
}

// ---- output projection: C(fp32) = A(bf16) * wo(bf16)^T + b. grid 256 ----
__global__ __launch_bounds__(512, 2) void out_gemm(
    const u16* __restrict__ A, const u16* __restrict__ W,
    const float* __restrict__ bias, float* __restrict__ C) {
    __shared__ __align__(16) u16 lds[65536];
    int bid = blockIdx.x;
    int wgid = (bid & 7) * 32 + (bid >> 3);
    int brow = wgid >> 4, bcol = wgid & 15;
    f32x4 acc[8][4];
    gemm256<64>(A + (size_t)brow * 256 * 4096, W + (size_t)bcol * 256 * 4096, lds, acc);
    const int t = threadIdx.x, l = t & 63, w = t >> 6;
    const int wmi = w >> 2, wni = w & 3, r = l & 15, qd = l >> 4;
#pragma unroll
    for (int n = 0; n < 4; ++n) {
        int col = bcol * 256 + wni * 64 + n * 16 + r;
        float bv = bias[col];
#pragma unroll
        for (int mt = 0; mt < 8; ++mt)
#pragma unroll
            for (int j = 0; j < 4; ++j) {
                int m = brow * 256 + wmi * 128 + mt * 16 + qd * 4 + j;
                C[(size_t)m * 4096 + col] = acc[mt][n][j] + bv;
            }
    }
}

// ---- flash MQA attention. grid 1024 blocks; LPT remap: heavy q-tiles first ----
__global__ __launch_bounds__(256, 2) void flash_mqa(
    const u16* __restrict__ Qb, const u16* __restrict__ Kb,
    const u16* __restrict__ Vt, u16* __restrict__ Ob) {
    __shared__ __align__(16) u16 sK[64 * 136];   // [kv][d]
    __shared__ __align__(16) u16 sV[128 * 72];   // [d][kv]
    __shared__ __align__(16) u16 sP[128 * 72];   // [q][kv]

    int t = threadIdx.x, lane = t & 63, w = t >> 6;
    int r = lane & 15, qd = lane >> 4;

    int fid = blockIdx.x + 16 * blockIdx.y + 512 * blockIdx.z;
    int qi  = 15 - (fid >> 6);
    int rem = fid & 63;
    int h   = rem & 31;
    size_t bt0 = (size_t)(rem >> 5) * 2048;
    int q0 = qi * 128;

    bf16x8 qf[2][4];
#pragma unroll
    for (int mt = 0; mt < 2; ++mt) {
        const u16* qp = Qb + (bt0 + q0 + w * 32 + mt * 16 + r) * 4096 + h * 128 + qd * 8;
#pragma unroll
        for (int kk = 0; kk < 4; ++kk) qf[mt][kk] = *(const bf16x8*)(qp + kk * 32);
    }

    f32x4 o[2][8], osum[2];
    float mrun[2][4];
#pragma unroll
    for (int mt = 0; mt < 2; ++mt) {
#pragma unroll
        for (int dn = 0; dn < 8; ++dn) o[mt][dn] = (f32x4){0.f, 0.f, 0.f, 0.f};
        osum[mt] = (f32x4){0.f, 0.f, 0.f, 0.f};
#pragma unroll
        for (int j = 0; j < 4; ++j) mrun[mt][j] = -1e30f;
    }

    union { uint4 v; bf16x8 b; } onesu;
    onesu.v = make_uint4(0x3F803F80u, 0x3F803F80u, 0x3F803F80u, 0x3F803F80u);
    const bf16x8 ones = onesu.b;

    int e = t * 8;
    int krr = e >> 7, kcc = e & 127;
    int vdd = e >> 6, vkv = e & 63;
    int ktiles = 2 * qi + 2;

    for (int kt = 0; kt < ktiles; ++kt) {
        int kb = kt * 64;
        const u16* kg = Kb + (bt0 + kb + krr) * 128 + kcc;
        u16* kl = sK + krr * 136 + kcc;
#pragma unroll
        for (int c = 0; c < 4; ++c)
            *(uint4*)(kl + c * 16 * 136) = *(const uint4*)(kg + (size_t)c * 16 * 128);
        const u16* vg = Vt + (size_t)vdd * 4096 + bt0 + kb + vkv;
        u16* vl = sV + vdd * 72 + vkv;
#pragma unroll
        for (int c = 0; c < 4; ++c)
            *(uint4*)(vl + c * 32 * 72) = *(const uint4*)(vg + (size_t)c * 32 * 4096);
        __syncthreads();

        f32x4 s[2][4];
#pragma unroll
        for (int mt = 0; mt < 2; ++mt)
#pragma unroll
            for (int nt = 0; nt < 4; ++nt) s[mt][nt] = (f32x4){0.f, 0.f, 0.f, 0.f};
#pragma unroll
        for (int kk = 0; kk < 4; ++kk) {
            bf16x8 kf[4];
#pragma unroll
            for (int nt = 0; nt < 4; ++nt)
                kf[nt] = *(const bf16x8*)(sK + (nt * 16 + r) * 136 + kk * 32 + qd * 8);
#pragma unroll
            for (int mt = 0; mt < 2; ++mt)
#pragma unroll
                for (int nt = 0; nt < 4; ++nt)
                    s[mt][nt] = __builtin_amdgcn_mfma_f32_16x16x32_bf16(qf[mt][kk], kf[nt], s[mt][nt], 0, 0, 0);
        }

#pragma unroll
        for (int mt = 0; mt < 2; ++mt) {
            int qrow0 = q0 + w * 32 + mt * 16 + qd * 4;
#pragma unroll
            for (int nt = 0; nt < 4; ++nt) {
                int kcol = kb + nt * 16 + r;
#pragma unroll
                for (int j = 0; j < 4; ++j)
                    s[mt][nt][j] = (kcol <= qrow0 + j) ? s[mt][nt][j] : -1e30f;
            }
#pragma unroll
            for (int j = 0; j < 4; ++j) {
                float mx = fmaxf(fmaxf(s[mt][0][j], s[mt][1][j]), fmaxf(s[mt][2][j], s[mt][3][j]));
                mx = fmaxf(mx, __shfl_xor(mx, 1));
                mx = fmaxf(mx, __shfl_xor(mx, 2));
                mx = fmaxf(mx, __shfl_xor(mx, 4));
                mx = fmaxf(mx, __shfl_xor(mx, 8));
                float mnew = fmaxf(mrun[mt][j], mx);
                float alpha = exp2f(mrun[mt][j] - mnew);
                mrun[mt][j] = mnew;
                u16* pp = sP + (size_t)(w * 32 + mt * 16 + qd * 4 + j) * 72;
#pragma unroll
                for (int nt = 0; nt < 4; ++nt)
                    pp[nt * 16 + r] = f2b_ru(exp2f(s[mt][nt][j] - mnew));
#pragma unroll
                for (int dn = 0; dn < 8; ++dn) o[mt][dn][j] *= alpha;
                osum[mt][j] *= alpha;
            }
        }

        __syncthreads();

#pragma unroll
        for (int kk = 0; kk < 2; ++kk) {
            bf16x8 pf[2];
#pragma unroll
            for (int mt = 0; mt < 2; ++mt) {
                pf[mt] = *(const bf16x8*)(sP + (w * 32 + mt * 16 + r) * 72 + kk * 32 + qd * 8);
                osum[mt] = __builtin_amdgcn_mfma_f32_16x16x32_bf16(pf[mt], ones, osum[mt], 0, 0, 0);
            }
#pragma unroll
            for (int dn = 0; dn < 8; ++dn) {
                bf16x8 vf = *(const bf16x8*)(sV + (dn * 16 + r) * 72 + kk * 32 + qd * 8);
#pragma unroll
                for (int mt = 0; mt < 2; ++mt)
                    o[mt][dn] = __builtin_amdgcn_mfma_f32_16x16x32_bf16(pf[mt], vf, o[mt][dn], 0, 0, 0);
            }
        }
        __syncthreads();
    }

#pragma unroll
    for (int mt = 0; mt < 2; ++mt)
#pragma unroll
        for (int j = 0; j < 4; ++j) {
            float inv = 1.0f / osum[mt][j];
            u16* op = Ob + (bt0 + q0 + w * 32 + mt * 16 + qd * 4 + j) * 4096 + h * 128;
#pragma unroll
            for (int dn = 0; dn < 8; ++dn) op[dn * 16 + r] = f2b(o[mt][dn][j] * inv);
        }
}

extern "C" void kernel_launch(void* const* d_in, const int* in_sizes, int n_in,
                              void* d_out, int out_size, void* d_ws, size_t ws_size,
                              hipStream_t stream) {
    const float* x   = (const float*)d_in[0];
    const float* wq  = (const float*)d_in[1];
    const float* wqb = (const float*)d_in[2];
    const float* wk  = (const float*)d_in[3];
    const float* wkb = (const float*)d_in[4];
    const float* wv  = (const float*)d_in[5];
    const float* wvb = (const float*)d_in[6];
    const float* wo  = (const float*)d_in[7];
    const float* wob = (const float*)d_in[8];

    const int NX = 4096 * 4096;   // x / wq / wo element counts
    const int NK = 128 * 4096;    // wk / wv element counts

    u16* xb   = (u16*)d_ws;                      // later Ob
    u16* wq16 = xb   + (size_t)NX;               // later wo16
    u16* wk16 = wq16 + (size_t)NX;               // wk|wv contiguous (kv_gemm needs it)
    u16* wv16 = wk16 + (size_t)NK;
    u16* Qb   = wv16 + (size_t)NK;               // first used as f32 KV-partial buffer
    u16* Kb   = Qb   + (size_t)NX;
    u16* Vt   = Kb   + (size_t)NK;
    u16* Ob   = xb;                              // alias (xb dead after q_gemm)
    u16* wo16 = wq16;                            // alias (wq16 dead after q_gemm)
    float* Pf = (float*)Qb;                      // 8*4096*256 f32 = 32 MiB = sizeof(Qb)
    float* out = (float*)d_out;

    cvt_f32_bf16<<<NX / 2048, 256, 0, stream>>>(x,  xb,   NX);
    cvt_f32_bf16<<<NX / 2048, 256, 0, stream>>>(wq, wq16, NX);
    cvt_f32_bf16<<<NK / 2048, 256, 0, stream>>>(wk, wk16, NK);
    cvt_f32_bf16<<<NK / 2048, 256, 0, stream>>>(wv, wv16, NK);

    kv_gemm<<<dim3(16, 8), 512, 0, stream>>>(xb, wk16, Pf);
    kv_reduce<<<4096, 256, 0, stream>>>(Pf, wkb, wvb, Kb, Vt);
    q_gemm<<<256, 512, 0, stream>>>(xb, wq16, wqb, Qb);       // overwrites Pf (dead)

    cvt_f32_bf16<<<NX / 2048, 256, 0, stream>>>(wo, wo16, NX);  // after q_gemm (region reuse)

    flash_mqa<<<dim3(16, 32, 2), 256, 0, stream>>>(Qb, Kb, Vt, Ob);
    out_gemm<<<256, 512, 0, stream>>>(Ob, wo16, wob, out);
}

// Round 3
// 591.558 us; speedup vs baseline: 1.2569x; 1.0632x over previous
//
#include <hip/hip_runtime.h>

typedef unsigned short u16;
using bf16x8 = __attribute__((ext_vector_type(8))) __bf16;
using f32x4  = __attribute__((ext_vector_type(4))) float;

// B=2, T=2048, D=4096, H=32, HD=128, HKV=1. M = B*T = 4096 token rows.

__device__ __forceinline__ u16 f2b(float f) {
    union { float f; unsigned int i; } x; x.f = f;
    unsigned int i = x.i + (((x.i >> 16) & 1u) + 0x7fffu);  // RNE
    return (u16)(i >> 16);
}
__device__ __forceinline__ void gload_lds16(const u16* g, u16* l) {
    __builtin_amdgcn_global_load_lds((const __attribute__((address_space(1))) void*)g,
                                     (__attribute__((address_space(3))) void*)l, 16, 0, 0);
}

// ---- fp32 -> bf16 conversion (vectorized, 8 elems/thread) ----
__global__ __launch_bounds__(256) void cvt_f32_bf16(const float* __restrict__ in,
                                                    u16* __restrict__ out, int n) {
    int i = (blockIdx.x * 256 + threadIdx.x) * 8;
    if (i >= n) return;
    float4 a = *(const float4*)(in + i);
    float4 b = *(const float4*)(in + i + 4);
    union { u16 u[8]; uint4 v; } o;
    o.u[0] = f2b(a.x); o.u[1] = f2b(a.y); o.u[2] = f2b(a.z); o.u[3] = f2b(a.w);
    o.u[4] = f2b(b.x); o.u[5] = f2b(b.y); o.u[6] = f2b(b.z); o.u[7] = f2b(b.w);
    *(uint4*)(out + i) = o.v;
}

// =====================================================================
// 256x256-tile 8-phase GEMM core (C = A * W^T, both row-major, K-stride 4096)
// 8 waves (2M x 4N), BK=64, double-buffered 128 KiB LDS, st_16x32 swizzle.
// =====================================================================

#define G_BAR()   __builtin_amdgcn_s_barrier()
#define G_LGKM0() asm volatile("s_waitcnt lgkmcnt(0)" ::: "memory")

struct GCtx {
    const u16* gA; const u16* gB;   // per-lane pre-swizzled staging sources
    int fro;                        // swizzled frag-read offset within subtile (u16)
    int dst;                        // lane dest within subtile (u16) = lane*8
    int wmi, wni;                   // wave tile coords (2 x 4)
    int rgA0, rgA1, rgB0, rgB1;     // per-wave rowgroup assignments for half-stages
    int w;
};

__device__ __forceinline__ void stg2(const GCtx& c, const u16* gb, int rg, int kt, u16* sb) {
    const u16* src = gb + (size_t)rg * 65536 + (size_t)kt * 64;   // rg*16 rows * 4096
    u16* d = sb + rg * 1024 + c.dst;                               // subtile (rg,cg) base
    gload_lds16(src,      d);
    gload_lds16(src + 32, d + 512);
}

template<int MODE>  // 0 = steady, 1 = first epilogue tile, 2 = last tile
__device__ __forceinline__ void tile_step(const GCtx& c, int u,
        u16* __restrict__ cA, u16* __restrict__ cB,
        u16* __restrict__ nA, u16* __restrict__ nB,
        f32x4 (&acc)[8][4]) {
    bf16x8 af[4][2], bf[2][2];
    // ---------------- P1: quadrant (mh0, nh0) ----------------
#pragma unroll
    for (int i = 0; i < 4; ++i) {
        const u16* p = cA + (((c.wmi * 8 + i) * 2) << 9) + c.fro;
        af[i][0] = *(const bf16x8*)(p);
        af[i][1] = *(const bf16x8*)(p + 512);
    }
#pragma unroll
    for (int n = 0; n < 2; ++n) {
        const u16* p = cB + (((c.wni * 4 + n) * 2) << 9) + c.fro;
        bf[n][0] = *(const bf16x8*)(p);
        bf[n][1] = *(const bf16x8*)(p + 512);
    }
    if (MODE < 2) stg2(c, c.gA, c.rgA1, u + 1, nA);
    G_BAR(); G_LGKM0();
    __builtin_amdgcn_s_setprio(1);
#pragma unroll
    for (int i = 0; i < 4; ++i)
#pragma unroll
        for (int n = 0; n < 2; ++n) {
            acc[i][n] = __builtin_amdgcn_mfma_f32_16x16x32_bf16(af[i][0], bf[n][0], acc[i][n], 0, 0, 0);
            acc[i][n] = __builtin_amdgcn_mfma_f32_16x16x32_bf16(af[i][1], bf[n][1], acc[i][n], 0, 0, 0);
        }
    __builtin_amdgcn_s_setprio(0);
    G_BAR();
    // ---------------- P2: quadrant (mh0, nh1) ----------------
#pragma unroll
    for (int n = 0; n < 2; ++n) {
        const u16* p = cB + (((c.wni * 4 + 2 + n) * 2) << 9) + c.fro;
        bf[n][0] = *(const bf16x8*)(p);
        bf[n][1] = *(const bf16x8*)(p + 512);
    }
    if (MODE < 2) stg2(c, c.gB, c.rgB0, u + 1, nB);
    G_BAR(); G_LGKM0();
    __builtin_amdgcn_s_setprio(1);
#pragma unroll
    for (int i = 0; i < 4; ++i)
#pragma unroll
        for (int n = 0; n < 2; ++n) {
            acc[i][2 + n] = __builtin_amdgcn_mfma_f32_16x16x32_bf16(af[i][0], bf[n][0], acc[i][2 + n], 0, 0, 0);
            acc[i][2 + n] = __builtin_amdgcn_mfma_f32_16x16x32_bf16(af[i][1], bf[n][1], acc[i][2 + n], 0, 0, 0);
        }
    __builtin_amdgcn_s_setprio(0);
    G_BAR();
    // ---------------- P3: quadrant (mh1, nh1) ----------------
#pragma unroll
    for (int i = 0; i < 4; ++i) {
        const u16* p = cA + (((c.wmi * 8 + 4 + i) * 2) << 9) + c.fro;
        af[i][0] = *(const bf16x8*)(p);
        af[i][1] = *(const bf16x8*)(p + 512);
    }
    if (MODE == 0) stg2(c, c.gA, c.rgA0, u + 2, cA);
    G_BAR(); G_LGKM0();
    __builtin_amdgcn_s_setprio(1);
#pragma unroll
    for (int i = 0; i < 4; ++i)
#pragma unroll
        for (int n = 0; n < 2; ++n) {
            acc[4 + i][2 + n] = __builtin_amdgcn_mfma_f32_16x16x32_bf16(af[i][0], bf[n][0], acc[4 + i][2 + n], 0, 0, 0);
            acc[4 + i][2 + n] = __builtin_amdgcn_mfma_f32_16x16x32_bf16(af[i][1], bf[n][1], acc[4 + i][2 + n], 0, 0, 0);
        }
    __builtin_amdgcn_s_setprio(0);
    G_BAR();
    // ---------------- P4: quadrant (mh1, nh0) ----------------
#pragma unroll
    for (int n = 0; n < 2; ++n) {
        const u16* p = cB + (((c.wni * 4 + n) * 2) << 9) + c.fro;
        bf[n][0] = *(const bf16x8*)(p);
        bf[n][1] = *(const bf16x8*)(p + 512);
    }
    if (MODE == 0) stg2(c, c.gB, c.rgB1, u + 2, cB);
    G_BAR(); G_LGKM0();
    __builtin_amdgcn_s_setprio(1);
#pragma unroll
    for (int i = 0; i < 4; ++i)
#pragma unroll
        for (int n = 0; n < 2; ++n) {
            acc[4 + i][n] = __builtin_amdgcn_mfma_f32_16x16x32_bf16(af[i][0], bf[n][0], acc[4 + i][n], 0, 0, 0);
            acc[4 + i][n] = __builtin_amdgcn_mfma_f32_16x16x32_bf16(af[i][1], bf[n][1], acc[4 + i][n], 0, 0, 0);
        }
    __builtin_amdgcn_s_setprio(0);
    if (MODE == 0) asm volatile("s_waitcnt vmcnt(4)" ::: "memory");
    if (MODE == 1) asm volatile("s_waitcnt vmcnt(0)" ::: "memory");
    G_BAR();
}

template<int NT>
__device__ __forceinline__ void gemm256(const u16* __restrict__ Ag,
                                        const u16* __restrict__ Bg,
                                        u16* __restrict__ lds,
                                        f32x4 (&acc)[8][4]) {
    const int t = threadIdx.x, l = t & 63, w = t >> 6;
    const int r = l & 15, qd = l >> 4, lr = l >> 2;
    const int co = ((l & 3) * 8) ^ (((l >> 5) & 1) << 4);  // inverse st_16x32 swizzle on source
    GCtx c;
    c.w = w; c.wmi = w >> 2; c.wni = w & 3;
    c.gA = Ag + (size_t)lr * 4096 + co;
    c.gB = Bg + (size_t)lr * 4096 + co;
    c.fro = r * 32 + ((qd * 8) ^ (((r >> 3) & 1) << 4));   // swizzled frag read
    c.dst = l * 8;
    c.rgA0 = (w & 3) | ((w & 4) << 1);        // {0,1,2,3,8,9,10,11}[w]
    c.rgA1 = c.rgA0 + 4;                       // {4..7,12..15}
    c.rgB0 = (w & 1) | ((w >> 1) << 2);        // {0,1,4,5,8,9,12,13}[w]
    c.rgB1 = c.rgB0 + 2;                       // {2,3,6,7,10,11,14,15}
    u16* sA0 = lds;          u16* sB0 = lds + 16384;
    u16* sA1 = lds + 32768;  u16* sB1 = lds + 49152;
#pragma unroll
    for (int i = 0; i < 8; ++i)
#pragma unroll
        for (int n = 0; n < 4; ++n) acc[i][n] = (f32x4){0.f, 0.f, 0.f, 0.f};
    // prologue: tile0 full (8 loads) + tile1 Amh0,Bnh1 (4 loads)
    stg2(c, c.gA, w, 0, sA0);     stg2(c, c.gA, w + 8, 0, sA0);
    stg2(c, c.gB, w, 0, sB0);     stg2(c, c.gB, w + 8, 0, sB0);
    stg2(c, c.gA, c.rgA0, 1, sA1);
    stg2(c, c.gB, c.rgB1, 1, sB1);
    asm volatile("s_waitcnt vmcnt(4)" ::: "memory");   // tile0 landed; tile1 in flight
    G_BAR();
#pragma unroll 1
    for (int u = 0; u + 2 < NT; u += 2) {
        tile_step<0>(c, u,     sA0, sB0, sA1, sB1, acc);
        tile_step<0>(c, u + 1, sA1, sB1, sA0, sB0, acc);
    }
    tile_step<1>(c, NT - 2, sA0, sB0, sA1, sB1, acc);
    tile_step<2>(c, NT - 1, sA1, sB1, sA0, sB0, acc);
}

// ---- Q projection: C = x * wq^T, pre-scaled. grid 256 (16x16, XCD-swizzled) ----
__global__ __launch_bounds__(512, 2) void q_gemm(
    const u16* __restrict__ x, const u16* __restrict__ wq,
    const float* __restrict__ wqb, u16* __restrict__ Qb) {
    __shared__ __align__(16) u16 lds[65536];   // 128 KiB
    int bid = blockIdx.x;
    int wgid = (bid & 7) * 32 + (bid >> 3);    // bijective (256 = 8*32)
    int brow = wgid >> 4, bcol = wgid & 15;
    f32x4 acc[8][4];
    gemm256<64>(x + (size_t)brow * 256 * 4096, wq + (size_t)bcol * 256 * 4096, lds, acc);
    const int t = threadIdx.x, l = t & 63, w = t >> 6;
    const int wmi = w >> 2, wni = w & 3, r = l & 15, qd = l >> 4;
    const float QSCALE = 0.08838834764831845f * 1.4426950408889634f;  // 1/sqrt(128)*log2(e)
#pragma unroll
    for (int n = 0; n < 4; ++n) {
        int col = bcol * 256 + wni * 64 + n * 16 + r;
        float bv = wqb[col];
#pragma unroll
        for (int mt = 0; mt < 8; ++mt)
#pragma unroll
            for (int j = 0; j < 4; ++j) {
                int m = brow * 256 + wmi * 128 + mt * 16 + qd * 4 + j;
                Qb[(size_t)m * 4096 + col] = f2b((acc[mt][n][j] + bv) * QSCALE);
            }
    }
}

// ---- K/V projection: K-split 8-phase GEMM into f32 partials. grid (16, 8) ----
__global__ __launch_bounds__(512, 2) void kv_gemm(
    const u16* __restrict__ x, const u16* __restrict__ wkv,
    float* __restrict__ P) {
    __shared__ __align__(16) u16 lds[65536];
    int brow = blockIdx.x;      // 0..15
    int slice = blockIdx.y;     // 0..7 (K chunk of 512)
    f32x4 acc[8][4];
    gemm256<8>(x + (size_t)brow * 256 * 4096 + slice * 512,
               wkv + slice * 512, lds, acc);
    const int t = threadIdx.x, l = t & 63, w = t >> 6;
    const int wmi = w >> 2, wni = w & 3, r = l & 15, qd = l >> 4;
    float* Pb = P + (size_t)slice * 4096 * 256;
#pragma unroll
    for (int n = 0; n < 4; ++n) {
        int nl = wni * 64 + n * 16 + r;
#pragma unroll
        for (int mt = 0; mt < 8; ++mt)
#pragma unroll
            for (int j = 0; j < 4; ++j) {
                int m = brow * 256 + wmi * 128 + mt * 16 + qd * 4 + j;
                Pb[(size_t)m * 256 + nl] = acc[mt][n][j];
            }
    }
}

// ---- reduce 8 K/V partials + bias -> Kb / Vt(bf16). grid 4096x256 ----
__global__ __launch_bounds__(256) void kv_reduce(const float* __restrict__ P,
        const float* __restrict__ wkb, const float* __restrict__ wvb,
        u16* __restrict__ Kb, u16* __restrict__ Vt) {
    int t = blockIdx.x * 256 + threadIdx.x;
    if (blockIdx.x < 2048) {                   // K half: nl fastest -> coalesced Kb
        int m = t >> 7, nl = t & 127;
        float s = 0.f;
#pragma unroll
        for (int sl = 0; sl < 8; ++sl) s += P[((size_t)sl * 4096 + m) * 256 + nl];
        Kb[(size_t)m * 128 + nl] = f2b(s + wkb[nl]);
    } else {                                    // V half: m fastest -> coalesced Vt rows
        int idx = t - 524288;
        int d = idx >> 12, m = idx & 4095;
        float s = 0.f;
#pragma unroll
        for (int sl = 0; sl < 8; ++sl) s += P[((size_t)sl * 4096 + m) * 256 + 128 + d];
        Vt[(size_t)d * 4096 + m] = f2b(s + wvb[d]);
    }
}

// ---- output projection: C(fp32) = A(bf16) * wo(bf16)^T + b. grid 256 ----
__global__ __launch_bounds__(512, 2) void out_gemm(
    const u16* __restrict__ A, const u16* __restrict__ W,
    const float* __restrict__ bias, float* __restrict__ C) {
    __shared__ __align__(16) u16 lds[65536];
    int bid = blockIdx.x;
    int wgid = (bid & 7) * 32 + (bid >> 3);
    int brow = wgid >> 4, bcol = wgid & 15;
    f32x4 acc[8][4];
    gemm256<64>(A + (size_t)brow * 256 * 4096, W + (size_t)bcol * 256 * 4096, lds, acc);
    const int t = threadIdx.x, l = t & 63, w = t >> 6;
    const int wmi = w >> 2, wni = w & 3, r = l & 15, qd = l >> 4;
#pragma unroll
    for (int n = 0; n < 4; ++n) {
        int col = bcol * 256 + wni * 64 + n * 16 + r;
        float bv = bias[col];
#pragma unroll
        for (int mt = 0; mt < 8; ++mt)
#pragma unroll
            for (int j = 0; j < 4; ++j) {
                int m = brow * 256 + wmi * 128 + mt * 16 + qd * 4 + j;
                C[(size_t)m * 4096 + col] = acc[mt][n][j] + bv;
            }
    }
}

// ---- flash MQA attention. grid 1024 blocks; LPT remap: heavy q-tiles first ----
// Swapped QK^T (mfma(K,Q)): lane holds kv-slices of ONE q-row -> in-lane row-max,
// packed b64 P-stores, wave-private sP (middle barrier -> lgkmcnt fence),
// defer-max rescale (THR=8 in log2 domain), setprio around MFMA clusters.
__global__ __launch_bounds__(256, 2) void flash_mqa(
    const u16* __restrict__ Qb, const u16* __restrict__ Kb,
    const u16* __restrict__ Vt, u16* __restrict__ Ob) {
    __shared__ __align__(16) u16 sK[64 * 136];   // [kv][d]
    __shared__ __align__(16) u16 sV[128 * 72];   // [d][kv]
    __shared__ __align__(16) u16 sP[128 * 72];   // [q][kv] (wave-private rows)

    int t = threadIdx.x, lane = t & 63, w = t >> 6;
    int r = lane & 15, qd = lane >> 4;

    int fid = blockIdx.x + 16 * blockIdx.y + 512 * blockIdx.z;
    int qi  = 15 - (fid >> 6);
    int rem = fid & 63;
    int h   = rem & 31;
    size_t bt0 = (size_t)(rem >> 5) * 2048;
    int q0 = qi * 128;

    // Q fragments (pre-scaled by scale*log2e); serve as B-operand in swapped QK^T
    bf16x8 qf[2][4];
#pragma unroll
    for (int mt = 0; mt < 2; ++mt) {
        const u16* qp = Qb + (bt0 + q0 + w * 32 + mt * 16 + r) * 4096 + h * 128 + qd * 8;
#pragma unroll
        for (int kk = 0; kk < 4; ++kk) qf[mt][kk] = *(const bf16x8*)(qp + kk * 32);
    }

    f32x4 o[2][8], osum[2];
    float mrun[2];
#pragma unroll
    for (int mt = 0; mt < 2; ++mt) {
#pragma unroll
        for (int dn = 0; dn < 8; ++dn) o[mt][dn] = (f32x4){0.f, 0.f, 0.f, 0.f};
        osum[mt] = (f32x4){0.f, 0.f, 0.f, 0.f};
        mrun[mt] = -1e30f;
    }

    // ones B-fragment for MFMA row-sum of P (softmax denominator)
    union { uint4 v; bf16x8 b; } onesu;
    onesu.v = make_uint4(0x3F803F80u, 0x3F803F80u, 0x3F803F80u, 0x3F803F80u);
    const bf16x8 ones = onesu.b;

    int e = t * 8;
    int krr = e >> 7, kcc = e & 127;
    int vdd = e >> 6, vkv = e & 63;
    int ktiles = 2 * qi + 2;
    const float THR = 8.0f;

    for (int kt = 0; kt < ktiles; ++kt) {
        int kb = kt * 64;
        const u16* kg = Kb + (bt0 + kb + krr) * 128 + kcc;
        u16* kl = sK + krr * 136 + kcc;
#pragma unroll
        for (int c = 0; c < 4; ++c)
            *(uint4*)(kl + c * 16 * 136) = *(const uint4*)(kg + (size_t)c * 16 * 128);
        const u16* vg = Vt + (size_t)vdd * 4096 + bt0 + kb + vkv;
        u16* vl = sV + vdd * 72 + vkv;
#pragma unroll
        for (int c = 0; c < 4; ++c)
            *(uint4*)(vl + c * 32 * 72) = *(const uint4*)(vg + (size_t)c * 32 * 4096);
        __syncthreads();

        // S^T = K Q^T (log2 units). lane: q = q0+w*32+mt*16+r; kv = kb+nt*16+qd*4+j
        f32x4 s2[2][4];
#pragma unroll
        for (int mt = 0; mt < 2; ++mt)
#pragma unroll
            for (int nt = 0; nt < 4; ++nt) s2[mt][nt] = (f32x4){0.f, 0.f, 0.f, 0.f};
        __builtin_amdgcn_s_setprio(1);
#pragma unroll
        for (int kk = 0; kk < 4; ++kk) {
            bf16x8 kf[4];
#pragma unroll
            for (int nt = 0; nt < 4; ++nt)
                kf[nt] = *(const bf16x8*)(sK + (nt * 16 + r) * 136 + kk * 32 + qd * 8);
#pragma unroll
            for (int mt = 0; mt < 2; ++mt)
#pragma unroll
                for (int nt = 0; nt < 4; ++nt)
                    s2[mt][nt] = __builtin_amdgcn_mfma_f32_16x16x32_bf16(kf[nt], qf[mt][kk], s2[mt][nt], 0, 0, 0);
        }
        __builtin_amdgcn_s_setprio(0);

        // causal mask + in-lane row max (+2 shuffles across qd groups)
        float mx[2];
        bool need = false;
#pragma unroll
        for (int mt = 0; mt < 2; ++mt) {
            int qg = q0 + w * 32 + mt * 16 + r;
            int kvb = kb + qd * 4;
#pragma unroll
            for (int nt = 0; nt < 4; ++nt)
#pragma unroll
                for (int j = 0; j < 4; ++j)
                    s2[mt][nt][j] = (kvb + nt * 16 + j <= qg) ? s2[mt][nt][j] : -1e30f;
            f32x4 vm;
#pragma unroll
            for (int j = 0; j < 4; ++j)
                vm[j] = fmaxf(fmaxf(s2[mt][0][j], s2[mt][1][j]), fmaxf(s2[mt][2][j], s2[mt][3][j]));
            float m0 = fmaxf(fmaxf(vm[0], vm[1]), fmaxf(vm[2], vm[3]));
            m0 = fmaxf(m0, __shfl_xor(m0, 16));
            m0 = fmaxf(m0, __shfl_xor(m0, 32));
            mx[mt] = m0;
            need = need || (m0 > mrun[mt] + THR);
        }

        // defer-max: rescale only when max grew past THR (wave-uniform branch)
        if (__any(need)) {
#pragma unroll
            for (int mt = 0; mt < 2; ++mt) {
                float mnew = fmaxf(mrun[mt], mx[mt]);
                float al = exp2f(mrun[mt] - mnew);
                mrun[mt] = mnew;
                // broadcast alpha from softmax-lane (q=r) to o-rows (q=qd*4+j)
#pragma unroll
                for (int j = 0; j < 4; ++j) {
                    float aj = __shfl(al, ((lane >> 4) << 2) + j);
#pragma unroll
                    for (int dn = 0; dn < 8; ++dn) o[mt][dn][j] *= aj;
                    osum[mt][j] *= aj;
                }
            }
        }

        // P = exp2(S - mrun), packed bf16x4 -> b64 store (kv-contiguous per lane)
#pragma unroll
        for (int mt = 0; mt < 2; ++mt) {
            u16* pp = sP + (size_t)(w * 32 + mt * 16 + r) * 72 + qd * 4;
#pragma unroll
            for (int nt = 0; nt < 4; ++nt) {
                union { __bf16 b[4]; uint2 u; } pk;
#pragma unroll
                for (int j = 0; j < 4; ++j)
                    pk.b[j] = (__bf16)exp2f(s2[mt][nt][j] - mrun[mt]);
                *(uint2*)(pp + nt * 16) = pk.u;
            }
        }

        // wave-private sP: wave-local fence is enough (no cross-wave rows)
        asm volatile("s_waitcnt lgkmcnt(0)" ::: "memory");
        __builtin_amdgcn_sched_barrier(0);

        // O += P V; osum += P * ones
        __builtin_amdgcn_s_setprio(1);
#pragma unroll
        for (int kk = 0; kk < 2; ++kk) {
            bf16x8 pf[2];
#pragma unroll
            for (int mt = 0; mt < 2; ++mt) {
                pf[mt] = *(const bf16x8*)(sP + (w * 32 + mt * 16 + r) * 72 + kk * 32 + qd * 8);
                osum[mt] = __builtin_amdgcn_mfma_f32_16x16x32_bf16(pf[mt], ones, osum[mt], 0, 0, 0);
            }
#pragma unroll
            for (int dn = 0; dn < 8; ++dn) {
                bf16x8 vf = *(const bf16x8*)(sV + (dn * 16 + r) * 72 + kk * 32 + qd * 8);
#pragma unroll
                for (int mt = 0; mt < 2; ++mt)
                    o[mt][dn] = __builtin_amdgcn_mfma_f32_16x16x32_bf16(pf[mt], vf, o[mt][dn], 0, 0, 0);
            }
        }
        __builtin_amdgcn_s_setprio(0);
        __syncthreads();   // before restaging sK/sV
    }

#pragma unroll
    for (int mt = 0; mt < 2; ++mt)
#pragma unroll
        for (int j = 0; j < 4; ++j) {
            float inv = 1.0f / osum[mt][j];
            u16* op = Ob + (bt0 + q0 + w * 32 + mt * 16 + qd * 4 + j) * 4096 + h * 128;
#pragma unroll
            for (int dn = 0; dn < 8; ++dn) op[dn * 16 + r] = f2b(o[mt][dn][j] * inv);
        }
}

extern "C" void kernel_launch(void* const* d_in, const int* in_sizes, int n_in,
                              void* d_out, int out_size, void* d_ws, size_t ws_size,
                              hipStream_t stream) {
    const float* x   = (const float*)d_in[0];
    const float* wq  = (const float*)d_in[1];
    const float* wqb = (const float*)d_in[2];
    const float* wk  = (const float*)d_in[3];
    const float* wkb = (const float*)d_in[4];
    const float* wv  = (const float*)d_in[5];
    const float* wvb = (const float*)d_in[6];
    const float* wo  = (const float*)d_in[7];
    const float* wob = (const float*)d_in[8];

    const int NX = 4096 * 4096;   // x / wq / wo element counts
    const int NK = 128 * 4096;    // wk / wv element counts

    u16* xb   = (u16*)d_ws;                      // later Ob
    u16* wq16 = xb   + (size_t)NX;               // later wo16
    u16* wk16 = wq16 + (size_t)NX;               // wk|wv contiguous (kv_gemm needs it)
    u16* wv16 = wk16 + (size_t)NK;
    u16* Qb   = wv16 + (size_t)NK;               // first used as f32 KV-partial buffer
    u16* Kb   = Qb   + (size_t)NX;
    u16* Vt   = Kb   + (size_t)NK;
    u16* Ob   = xb;                              // alias (xb dead after q_gemm)
    u16* wo16 = wq16;                            // alias (wq16 dead after q_gemm)
    float* Pf = (float*)Qb;                      // 8*4096*256 f32 = 32 MiB = sizeof(Qb)
    float* out = (float*)d_out;

    cvt_f32_bf16<<<NX / 2048, 256, 0, stream>>>(x,  xb,   NX);
    cvt_f32_bf16<<<NX / 2048, 256, 0, stream>>>(wq, wq16, NX);
    cvt_f32_bf16<<<NK / 2048, 256, 0, stream>>>(wk, wk16, NK);
    cvt_f32_bf16<<<NK / 2048, 256, 0, stream>>>(wv, wv16, NK);

    kv_gemm<<<dim3(16, 8), 512, 0, stream>>>(xb, wk16, Pf);
    kv_reduce<<<4096, 256, 0, stream>>>(Pf, wkb, wvb, Kb, Vt);
    q_gemm<<<256, 512, 0, stream>>>(xb, wq16, wqb, Qb);       // overwrites Pf (dead)

    cvt_f32_bf16<<<NX / 2048, 256, 0, stream>>>(wo, wo16, NX);  // after q_gemm (region reuse)

    flash_mqa<<<dim3(16, 32, 2), 256, 0, stream>>>(Qb, Kb, Vt, Ob);
    out_gemm<<<256, 512, 0, stream>>>(Ob, wo16, wob, out);
}